// Round 4
// baseline (1288.585 us; speedup 1.0000x reference)
//
#include <hip/hip_runtime.h>

#define TT 2048
#define DD 1024
#define ND3 3072
#define LL 4
#define MAXIT 12

typedef float f32x4 __attribute__((ext_vector_type(4)));
typedef __bf16 bf16x8 __attribute__((ext_vector_type(8)));

__device__ __forceinline__ float sigmoidf_(float x) { return 1.f / (1.f + __expf(-x)); }

__device__ __forceinline__ float gru_out(float xr, float xz, float xn,
                                         float hr, float hz, float hn, float hp)
{
    float rg = sigmoidf_(xr + hr);
    float zg = sigmoidf_(xz + hz);
    float ng = tanhf(xn + rg * hn);
    return (1.f - zg) * ng + zg * hp;
}

__device__ __forceinline__ ushort f2bf(float x)
{
    unsigned u = __builtin_bit_cast(unsigned, x);
    return (ushort)((u + 0x7FFFu + ((u >> 16) & 1u)) >> 16);
}

__device__ __forceinline__ float bf2f(ushort u)
{
    return __builtin_bit_cast(float, ((unsigned)u) << 16);
}

__device__ __forceinline__ void gld_lds16(const void* g, void* l)
{
    __builtin_amdgcn_global_load_lds(
        (const __attribute__((address_space(1))) unsigned int*)g,
        (__attribute__((address_space(3))) unsigned int*)l, 16, 0, 0);
}

// ---------------------------------------------------------------------------
// Episode segmentation + counting sort (descending length). One block, parallel.
// g_nact[i] = #{episodes with len > i}, i=0..MAXIT (g_nact[0] = n_ep).
// ---------------------------------------------------------------------------
__global__ __launch_bounds__(256)
void seg_kernel(const int* __restrict__ term, int* __restrict__ g_start,
                int* __restrict__ g_len, int* __restrict__ g_perm,
                int* __restrict__ g_nact)
{
    __shared__ int s_start[TT + 1];
    __shared__ int s_len[TT];
    __shared__ int s_hist[TT + 1];
    __shared__ int s_base[TT + 1];
    __shared__ int s_p[256];
    __shared__ int s_wsum[33];
    __shared__ int s_n;
    int tid = threadIdx.x, lane = tid & 63, wv = tid >> 6;

    for (int i = tid; i <= TT; i += 256) s_hist[i] = 0;

    unsigned long long msk[8];
#pragma unroll
    for (int p = 0; p < 8; ++p) {
        int t = p * 256 + tid;
        int bit = (t == 0) || (term[t] != 0);
        unsigned long long m = __ballot(bit);
        msk[p] = m;
        if (lane == 0) s_wsum[p * 4 + wv] = __popcll(m);
    }
    __syncthreads();
    if (tid == 0) {
        int run = 0;
        for (int i = 0; i < 32; ++i) { int v = s_wsum[i]; s_wsum[i] = run; run += v; }
        s_n = run;
    }
    __syncthreads();
    int n = s_n;
#pragma unroll
    for (int p = 0; p < 8; ++p) {
        int t = p * 256 + tid;
        unsigned long long m = msk[p];
        if ((m >> lane) & 1ull) {
            int e = s_wsum[p * 4 + wv] + __popcll(m & ((1ull << lane) - 1ull));
            s_start[e] = t;
        }
    }
    if (tid == 0) s_start[n] = TT;
    __syncthreads();
    for (int e = tid; e < n; e += 256) {
        int L = s_start[e + 1] - s_start[e];
        s_len[e] = L;
        atomicAdd(&s_hist[L], 1);
    }
    __syncthreads();
    // suffix sums: s_base[L] = #{len > L} for L=1..TT (two-level scan)
    int lo = 8 * tid + 1;
    int p_i = 0;
#pragma unroll
    for (int j = 0; j < 8; ++j) p_i += s_hist[lo + j];
    s_p[tid] = p_i;
    __syncthreads();
    if (tid < 64) {
        int q0 = s_p[tid * 4], q1 = s_p[tid * 4 + 1], q2 = s_p[tid * 4 + 2], q3 = s_p[tid * 4 + 3];
        int q = q0 + q1 + q2 + q3;
        int acc = q;
        for (int off = 1; off < 64; off <<= 1) {
            int v = __shfl_down(acc, off);
            if (lane + off < 64) acc += v;
        }
        int ex = acc - q;   // sum over lanes > lane
        s_p[tid * 4 + 3] = ex;
        s_p[tid * 4 + 2] = ex + q3;
        s_p[tid * 4 + 1] = ex + q3 + q2;
        s_p[tid * 4 + 0] = ex + q3 + q2 + q1;
    }
    __syncthreads();
    int running = s_p[tid];
    for (int j = 7; j >= 0; --j) {
        s_base[lo + j] = running;
        running += s_hist[lo + j];
    }
    __syncthreads();
    if (tid == 0) g_nact[0] = n;
    if (tid >= 1 && tid <= MAXIT) g_nact[tid] = s_base[tid];
    __syncthreads();
    for (int e = tid; e < n; e += 256) {
        g_start[e] = s_start[e];
        int L = s_len[e];
        g_len[e] = L;
        int pos = atomicAdd(&s_base[L], 1);
        g_perm[pos] = e;
    }
}

// ---------------------------------------------------------------------------
// fp32 -> bf16 cast (vectorized), n multiple of 4
// ---------------------------------------------------------------------------
__global__ __launch_bounds__(256)
void cast_bf(const float* __restrict__ src, ushort* __restrict__ dst, int n)
{
    int base = (blockIdx.x * 256 + threadIdx.x) * 4;
    if (base < n) {
        float4 v = *(const float4*)(src + base);
        ushort4 o;
        o.x = f2bf(v.x); o.y = f2bf(v.y); o.z = f2bf(v.z); o.w = f2bf(v.w);
        *(ushort4*)(dst + base) = o;
    }
}

// ---------------------------------------------------------------------------
// Transpose + cast ALL weight matrices (both kinds, all layers) in one launch.
// z = l*2 + kind; kind 0: Wi[l] -> WT_all[l], kind 1: Wh[l] -> WhT_all[l].
// src [DD][ND3] fp32 -> dst [ND3][DD] bf16.
// ---------------------------------------------------------------------------
__global__ __launch_bounds__(256)
void transcast_all(const float* __restrict__ Wi, const float* __restrict__ Wh,
                   ushort* __restrict__ WT_all, ushort* __restrict__ WhT_all)
{
    int z = blockIdx.z;
    int l = z >> 1;
    const float* src = ((z & 1) ? Wh : Wi) + (size_t)l * DD * ND3;
    ushort* dst = ((z & 1) ? WhT_all : WT_all) + (size_t)l * ND3 * DD;
    __shared__ float tile[64][65];
    int tid = threadIdx.x;
    int n0 = blockIdx.x * 64, k0 = blockIdx.y * 64;
#pragma unroll
    for (int i = 0; i < 16; ++i) {
        int idx = i * 256 + tid;
        int r = idx >> 6, c = idx & 63;
        tile[r][c] = src[(size_t)(k0 + r) * ND3 + n0 + c];
    }
    __syncthreads();
#pragma unroll
    for (int i = 0; i < 8; ++i) {
        int idx = i * 256 + tid;
        int nr = idx >> 5, kp = idx & 31;
        float a = tile[kp * 2][nr], b = tile[kp * 2 + 1][nr];
        unsigned pa = (unsigned)f2bf(a) | ((unsigned)f2bf(b) << 16);
        *(unsigned*)&dst[(size_t)(n0 + nr) * DD + k0 + kp * 2] = pa;
    }
}

// ---------------------------------------------------------------------------
// Phase A GEMM (bf16 MFMA): C[2048][3072] = A[2048][1024] * BT[3072][1024]^T
// 128x128 tile, 4 waves (2x2), BK=32, global_load_lds staging, XOR k-slot
// swizzle. Output stored as bf16. (unchanged from round 3 — verified)
// ---------------------------------------------------------------------------
__global__ __launch_bounds__(256)
void gemm_mfma(const ushort* __restrict__ A, const ushort* __restrict__ BT,
               ushort* __restrict__ C)
{
    __shared__ __align__(16) ushort As[128 * 32];
    __shared__ __align__(16) ushort Bs[128 * 32];
    int tid = threadIdx.x, lane = tid & 63, wv = tid >> 6;
    int m0 = blockIdx.y * 128, n0 = blockIdx.x * 128;
    int wr = wv >> 1, wc = wv & 1;
    f32x4 acc[4][4] = {};

    int ci0 = tid, ci1 = 256 + tid;
    int r0s = ci0 >> 2, r1s = ci1 >> 2;
    int ss0 = (ci0 & 3) ^ ((r0s >> 1) & 3);
    int ss1 = (ci1 & 3) ^ ((r1s >> 1) & 3);
    const ushort* Ar0 = A + (size_t)(m0 + r0s) * DD + ss0 * 8;
    const ushort* Ar1 = A + (size_t)(m0 + r1s) * DD + ss1 * 8;
    const ushort* Br0 = BT + (size_t)(n0 + r0s) * DD + ss0 * 8;
    const ushort* Br1 = BT + (size_t)(n0 + r1s) * DD + ss1 * 8;

    int g = lane >> 4, fr = lane & 15;

    for (int k0 = 0; k0 < DD; k0 += 32) {
        gld_lds16(Ar0 + k0, (char*)As + wv * 1024);
        gld_lds16(Ar1 + k0, (char*)As + 4096 + wv * 1024);
        gld_lds16(Br0 + k0, (char*)Bs + wv * 1024);
        gld_lds16(Br1 + k0, (char*)Bs + 4096 + wv * 1024);
        __syncthreads();

        bf16x8 af[4], bb[4];
#pragma unroll
        for (int mi = 0; mi < 4; ++mi) {
            int row = wr * 64 + mi * 16 + fr;
            int slot = g ^ ((row >> 1) & 3);
            af[mi] = *(const bf16x8*)(As + row * 32 + slot * 8);
        }
#pragma unroll
        for (int ni = 0; ni < 4; ++ni) {
            int row = wc * 64 + ni * 16 + fr;
            int slot = g ^ ((row >> 1) & 3);
            bb[ni] = *(const bf16x8*)(Bs + row * 32 + slot * 8);
        }
#pragma unroll
        for (int mi = 0; mi < 4; ++mi)
#pragma unroll
            for (int ni = 0; ni < 4; ++ni)
                acc[mi][ni] = __builtin_amdgcn_mfma_f32_16x16x32_bf16(
                    af[mi], bb[ni], acc[mi][ni], 0, 0, 0);
        __syncthreads();
    }

    int orow = (lane >> 4) * 4, ocol = lane & 15;
#pragma unroll
    for (int mi = 0; mi < 4; ++mi)
#pragma unroll
        for (int ni = 0; ni < 4; ++ni)
#pragma unroll
            for (int r2 = 0; r2 < 4; ++r2)
                C[(size_t)(m0 + wr * 64 + mi * 16 + orow + r2) * ND3 +
                  n0 + wc * 64 + ni * 16 + ocol] = f2bf(acc[mi][ni][r2]);
}

// ---------------------------------------------------------------------------
// Iteration 0: h_in = 0 (or last_states for the t==0 episode).
// ---------------------------------------------------------------------------
__global__ __launch_bounds__(256)
void it0_kernel(const ushort* __restrict__ xp, const float* __restrict__ Wh,
                const float* __restrict__ bh, const float* __restrict__ h0g,
                const int* __restrict__ term, float* __restrict__ Hnext,
                ushort* __restrict__ Hbfn, ushort* __restrict__ ybf,
                float* __restrict__ yf32, float* __restrict__ finals,
                const int* __restrict__ g_start, const int* __restrict__ g_perm,
                const int* __restrict__ g_nact)
{
    int M = g_nact[0];
    int r = blockIdx.x;
    if (r >= M) return;
    int e = g_perm[r];
    int t = g_start[e];
    int tid = threadIdx.x;
    bool useh0 = (t == 0) && (term[0] == 0);
    __shared__ float h0s[DD];
    __shared__ int s_nz;
    if (tid == 0) s_nz = 0;
    __syncthreads();
    if (useh0) {
        int nz = 0;
#pragma unroll
        for (int j = 0; j < 4; ++j) {
            float v = h0g[tid + j * 256];
            h0s[tid + j * 256] = v;
            nz |= (v != 0.f) ? 1 : 0;
        }
        if (nz) atomicOr(&s_nz, 1);
    }
    __syncthreads();
    bool gemv = useh0 && (s_nz != 0);
#pragma unroll
    for (int j = 0; j < 4; ++j) {
        int c = tid + j * 256;
        float hr = bh[c], hz = bh[DD + c], hn = bh[2 * DD + c];
        if (gemv) {
            for (int k = 0; k < DD; ++k) {
                float hv = h0s[k];
                hr += hv * Wh[(size_t)k * ND3 + c];
                hz += hv * Wh[(size_t)k * ND3 + DD + c];
                hn += hv * Wh[(size_t)k * ND3 + 2 * DD + c];
            }
        }
        float hp = useh0 ? h0s[c] : 0.f;
        float xr = bf2f(xp[(size_t)t * ND3 + c]);
        float xz = bf2f(xp[(size_t)t * ND3 + DD + c]);
        float xn = bf2f(xp[(size_t)t * ND3 + 2 * DD + c]);
        float hnew = gru_out(xr, xz, xn, hr, hz, hn, hp);
        Hnext[(size_t)e * DD + c] = hnew;
        Hbfn[(size_t)e * DD + c] = f2bf(hnew);
        if (yf32) yf32[(size_t)t * DD + c] = hnew;
        else      ybf[(size_t)t * DD + c] = f2bf(hnew);
        if (t == TT - 1) finals[c] = hnew;
    }
}

// ---------------------------------------------------------------------------
// Iteration i>=1 (MFMA, LDS-free, barrier-free):
// hp_gemm = Hbf_active @ WhT^T, fused gates + state update.
// 512 threads / 8 waves. Tile: 32 rows x (64 hcols x 3 gates).
// MFMA fragments are loaded DIRECTLY from global (k-contiguous layouts):
//   A: lane holds Hbf[episode(row=lane&15)][k0 + (lane>>4)*8 ..+8]
//   B: lane holds WhT[col=lane&15-based][same k slice]
// B panels (<=32KB/wave) become L1-resident; no barriers -> compiler pipelines.
// ---------------------------------------------------------------------------
__global__ __launch_bounds__(512)
void iter_mfma(int it, const float* __restrict__ Hp, float* __restrict__ Hn,
               const ushort* __restrict__ Hbfp, ushort* __restrict__ Hbfn,
               const ushort* __restrict__ xp, const ushort* __restrict__ WhT,
               const float* __restrict__ bh, ushort* __restrict__ ybf,
               float* __restrict__ yf32, float* __restrict__ finals,
               const int* __restrict__ g_start, const int* __restrict__ g_perm,
               const int* __restrict__ g_nact)
{
    int M = g_nact[it];
    int r0 = blockIdx.y * 32;
    if (r0 >= M) return;
    int c0 = blockIdx.x * 64;
    int tid = threadIdx.x, lane = tid & 63, wv = tid >> 6;
    int fr = lane & 15, g = lane >> 4;
    int rw = (wv & 1) * 16, hw = (wv >> 1) * 16;

    // A fragment source: this lane's episode row
    int ar = r0 + rw + fr;
    if (ar > M - 1) ar = M - 1;
    int eA = g_perm[ar];
    const ushort* aptr = Hbfp + (size_t)eA * DD + g * 8;
    // B fragment sources (one per gate)
    int coln = c0 + hw + fr;
    const ushort* bptr0 = WhT + (size_t)(0 * DD + coln) * DD + g * 8;
    const ushort* bptr1 = WhT + (size_t)(1 * DD + coln) * DD + g * 8;
    const ushort* bptr2 = WhT + (size_t)(2 * DD + coln) * DD + g * 8;

    f32x4 acc0 = {}, acc1 = {}, acc2 = {};
#pragma unroll 4
    for (int k0 = 0; k0 < DD; k0 += 32) {
        bf16x8 af = *(const bf16x8*)(aptr + k0);
        bf16x8 b0 = *(const bf16x8*)(bptr0 + k0);
        bf16x8 b1 = *(const bf16x8*)(bptr1 + k0);
        bf16x8 b2 = *(const bf16x8*)(bptr2 + k0);
        acc0 = __builtin_amdgcn_mfma_f32_16x16x32_bf16(af, b0, acc0, 0, 0, 0);
        acc1 = __builtin_amdgcn_mfma_f32_16x16x32_bf16(af, b1, acc1, 0, 0, 0);
        acc2 = __builtin_amdgcn_mfma_f32_16x16x32_bf16(af, b2, acc2, 0, 0, 0);
    }

    int col = c0 + hw + fr;
#pragma unroll
    for (int r2 = 0; r2 < 4; ++r2) {
        int row = rw + g * 4 + r2;
        int r = r0 + row;
        if (r >= M) continue;
        int e = g_perm[r];
        int t = g_start[e] + it;
        float hr = acc0[r2] + bh[col];
        float hz = acc1[r2] + bh[DD + col];
        float hn = acc2[r2] + bh[2 * DD + col];
        float xr = bf2f(xp[(size_t)t * ND3 + col]);
        float xz = bf2f(xp[(size_t)t * ND3 + DD + col]);
        float xn = bf2f(xp[(size_t)t * ND3 + 2 * DD + col]);
        float hp = Hp[(size_t)e * DD + col];
        float hnew = gru_out(xr, xz, xn, hr, hz, hn, hp);
        Hn[(size_t)e * DD + col] = hnew;
        Hbfn[(size_t)e * DD + col] = f2bf(hnew);
        if (yf32) yf32[(size_t)t * DD + col] = hnew;
        else      ybf[(size_t)t * DD + col] = f2bf(hnew);
        if (t == TT - 1) finals[col] = hnew;
    }
}

// ---------------------------------------------------------------------------
// Cleanup: serially finish any episode with len > MAXIT (normally none/few).
// ---------------------------------------------------------------------------
__global__ __launch_bounds__(256)
void cleanup_kernel(const float* __restrict__ Hlast, const ushort* __restrict__ xp,
                    const float* __restrict__ Wh, const float* __restrict__ bh,
                    ushort* __restrict__ ybf, float* __restrict__ yf32,
                    float* __restrict__ finals, const int* __restrict__ g_start,
                    const int* __restrict__ g_len, const int* __restrict__ g_perm,
                    const int* __restrict__ g_nact)
{
    int Mt = g_nact[MAXIT];
    if (Mt == 0) return;
    __shared__ float h[DD];
    int tid = threadIdx.x;
    for (int r = blockIdx.x; r < Mt; r += gridDim.x) {
        int e = g_perm[r];
        int s0 = g_start[e];
        int L = g_len[e];
#pragma unroll
        for (int j = 0; j < 4; ++j) h[tid + j * 256] = Hlast[(size_t)e * DD + tid + j * 256];
        __syncthreads();
        for (int i = MAXIT; i < L; ++i) {
            int t = s0 + i;
            float hnew[4];
#pragma unroll
            for (int j = 0; j < 4; ++j) {
                int c = tid + j * 256;
                float hr = bh[c], hz = bh[DD + c], hn = bh[2 * DD + c];
                for (int k = 0; k < DD; ++k) {
                    float hv = h[k];
                    hr += hv * Wh[(size_t)k * ND3 + c];
                    hz += hv * Wh[(size_t)k * ND3 + DD + c];
                    hn += hv * Wh[(size_t)k * ND3 + 2 * DD + c];
                }
                float xr = bf2f(xp[(size_t)t * ND3 + c]);
                float xz = bf2f(xp[(size_t)t * ND3 + DD + c]);
                float xn = bf2f(xp[(size_t)t * ND3 + 2 * DD + c]);
                float hp = h[c];
                hnew[j] = gru_out(xr, xz, xn, hr, hz, hn, hp);
                if (yf32) yf32[(size_t)t * DD + c] = hnew[j];
                else      ybf[(size_t)t * DD + c] = f2bf(hnew[j]);
                if (t == TT - 1) finals[c] = hnew[j];
            }
            __syncthreads();
#pragma unroll
            for (int j = 0; j < 4; ++j) h[tid + j * 256] = hnew[j];
            __syncthreads();
        }
        __syncthreads();
    }
}

// ---------------------------------------------------------------------------
extern "C" void kernel_launch(void* const* d_in, const int* in_sizes, int n_in,
                              void* d_out, int out_size, void* d_ws, size_t ws_size,
                              hipStream_t stream)
{
    const float* x_in = (const float*)d_in[0];
    const int*   term = (const int*)d_in[1];
    const float* h0   = (const float*)d_in[2];
    const float* Wi   = (const float*)d_in[3];
    const float* Wh   = (const float*)d_in[4];
    const float* bh   = (const float*)d_in[5];
    float* out = (float*)d_out;

    ushort* xp      = (ushort*)d_ws;                      // TT*ND3 bf16
    float*  Hb0     = (float*)(xp + (size_t)TT * ND3);    // TT*DD fp32
    float*  Hb1     = Hb0 + (size_t)TT * DD;              // TT*DD fp32
    ushort* Hbf0    = (ushort*)(Hb1 + (size_t)TT * DD);   // TT*DD bf16
    ushort* Hbf1    = Hbf0 + (size_t)TT * DD;             // TT*DD bf16
    ushort* Xbf     = Hbf1 + (size_t)TT * DD;             // TT*DD bf16
    ushort* Yb0     = Xbf + (size_t)TT * DD;              // TT*DD bf16
    ushort* Yb1     = Yb0 + (size_t)TT * DD;              // TT*DD bf16
    ushort* WT_all  = Yb1 + (size_t)TT * DD;              // LL*ND3*DD bf16
    ushort* WhT_all = WT_all + (size_t)LL * ND3 * DD;     // LL*ND3*DD bf16
    int* ib      = (int*)(WhT_all + (size_t)LL * ND3 * DD);
    int* g_start = ib;
    int* g_len   = ib + TT;
    int* g_perm  = ib + 2 * TT;
    int* g_nact  = ib + 3 * TT;

    seg_kernel<<<1, 256, 0, stream>>>(term, g_start, g_len, g_perm, g_nact);
    cast_bf<<<(TT * DD / 4 + 255) / 256, 256, 0, stream>>>(x_in, Xbf, TT * DD);
    transcast_all<<<dim3(ND3 / 64, DD / 64, 2 * LL), 256, 0, stream>>>(
        Wi, Wh, WT_all, WhT_all);

    const ushort* Abf[4] = { Xbf, Yb0, Yb1, Yb0 };
    ushort*       Ybo[4] = { Yb0, Yb1, Yb0, nullptr };

    for (int l = 0; l < LL; ++l) {
        const float* Whl = Wh + (size_t)l * DD * ND3;
        const float* bhl = bh + (size_t)l * ND3;
        const ushort* WTl  = WT_all + (size_t)l * ND3 * DD;
        const ushort* WhTl = WhT_all + (size_t)l * ND3 * DD;
        float* yf32 = (l == LL - 1) ? out : nullptr;
        ushort* ybf = Ybo[l];
        float* finals = out + (size_t)TT * DD + (size_t)l * DD;

        gemm_mfma<<<dim3(ND3 / 128, TT / 128), 256, 0, stream>>>(Abf[l], WTl, xp);

        it0_kernel<<<TT, 256, 0, stream>>>(xp, Whl, bhl, h0 + (size_t)l * DD, term,
                                           Hb0, Hbf0, ybf, yf32, finals,
                                           g_start, g_perm, g_nact);

        for (int it = 1; it < MAXIT; ++it) {
            float*  Hp   = (it & 1) ? Hb0 : Hb1;
            float*  Hn   = (it & 1) ? Hb1 : Hb0;
            ushort* Hbfp = (it & 1) ? Hbf0 : Hbf1;
            ushort* Hbfn = (it & 1) ? Hbf1 : Hbf0;
            int maxrows = TT / (it + 1);
            dim3 grd(DD / 64, (maxrows + 31) / 32);
            iter_mfma<<<grd, 512, 0, stream>>>(it, Hp, Hn, Hbfp, Hbfn, xp, WhTl,
                                               bhl, ybf, yf32, finals,
                                               g_start, g_perm, g_nact);
        }

        float* Hlast = ((MAXIT - 1) & 1) ? Hb1 : Hb0;
        cleanup_kernel<<<64, 256, 0, stream>>>(Hlast, xp, Whl, bhl, ybf, yf32,
                                               finals, g_start, g_len, g_perm,
                                               g_nact);
    }
}

// Round 5
// 711.689 us; speedup vs baseline: 1.8106x; 1.8106x over previous
//
#include <hip/hip_runtime.h>

#define TT 2048
#define DD 1024
#define ND3 3072
#define LL 4
#define MAXIT 12

typedef float f32x4 __attribute__((ext_vector_type(4)));
typedef __bf16 bf16x8 __attribute__((ext_vector_type(8)));

__device__ __forceinline__ float sigmoidf_(float x) { return 1.f / (1.f + __expf(-x)); }

__device__ __forceinline__ float gru_out(float xr, float xz, float xn,
                                         float hr, float hz, float hn, float hp)
{
    float rg = sigmoidf_(xr + hr);
    float zg = sigmoidf_(xz + hz);
    float ng = tanhf(xn + rg * hn);
    return (1.f - zg) * ng + zg * hp;
}

__device__ __forceinline__ ushort f2bf(float x)
{
    unsigned u = __builtin_bit_cast(unsigned, x);
    return (ushort)((u + 0x7FFFu + ((u >> 16) & 1u)) >> 16);
}

__device__ __forceinline__ float bf2f(ushort u)
{
    return __builtin_bit_cast(float, ((unsigned)u) << 16);
}

__device__ __forceinline__ void gld_lds16(const void* g, void* l)
{
    __builtin_amdgcn_global_load_lds(
        (const __attribute__((address_space(1))) unsigned int*)g,
        (__attribute__((address_space(3))) unsigned int*)l, 16, 0, 0);
}

// ---------------------------------------------------------------------------
// Episode segmentation + counting sort (descending length). One block, parallel.
// ---------------------------------------------------------------------------
__global__ __launch_bounds__(256)
void seg_kernel(const int* __restrict__ term, int* __restrict__ g_start,
                int* __restrict__ g_len, int* __restrict__ g_perm,
                int* __restrict__ g_nact)
{
    __shared__ int s_start[TT + 1];
    __shared__ int s_len[TT];
    __shared__ int s_hist[TT + 1];
    __shared__ int s_base[TT + 1];
    __shared__ int s_p[256];
    __shared__ int s_wsum[33];
    __shared__ int s_n;
    int tid = threadIdx.x, lane = tid & 63, wv = tid >> 6;

    for (int i = tid; i <= TT; i += 256) s_hist[i] = 0;

    unsigned long long msk[8];
#pragma unroll
    for (int p = 0; p < 8; ++p) {
        int t = p * 256 + tid;
        int bit = (t == 0) || (term[t] != 0);
        unsigned long long m = __ballot(bit);
        msk[p] = m;
        if (lane == 0) s_wsum[p * 4 + wv] = __popcll(m);
    }
    __syncthreads();
    if (tid == 0) {
        int run = 0;
        for (int i = 0; i < 32; ++i) { int v = s_wsum[i]; s_wsum[i] = run; run += v; }
        s_n = run;
    }
    __syncthreads();
    int n = s_n;
#pragma unroll
    for (int p = 0; p < 8; ++p) {
        int t = p * 256 + tid;
        unsigned long long m = msk[p];
        if ((m >> lane) & 1ull) {
            int e = s_wsum[p * 4 + wv] + __popcll(m & ((1ull << lane) - 1ull));
            s_start[e] = t;
        }
    }
    if (tid == 0) s_start[n] = TT;
    __syncthreads();
    for (int e = tid; e < n; e += 256) {
        int L = s_start[e + 1] - s_start[e];
        s_len[e] = L;
        atomicAdd(&s_hist[L], 1);
    }
    __syncthreads();
    int lo = 8 * tid + 1;
    int p_i = 0;
#pragma unroll
    for (int j = 0; j < 8; ++j) p_i += s_hist[lo + j];
    s_p[tid] = p_i;
    __syncthreads();
    if (tid < 64) {
        int q0 = s_p[tid * 4], q1 = s_p[tid * 4 + 1], q2 = s_p[tid * 4 + 2], q3 = s_p[tid * 4 + 3];
        int q = q0 + q1 + q2 + q3;
        int acc = q;
        for (int off = 1; off < 64; off <<= 1) {
            int v = __shfl_down(acc, off);
            if (lane + off < 64) acc += v;
        }
        int ex = acc - q;
        s_p[tid * 4 + 3] = ex;
        s_p[tid * 4 + 2] = ex + q3;
        s_p[tid * 4 + 1] = ex + q3 + q2;
        s_p[tid * 4 + 0] = ex + q3 + q2 + q1;
    }
    __syncthreads();
    int running = s_p[tid];
    for (int j = 7; j >= 0; --j) {
        s_base[lo + j] = running;
        running += s_hist[lo + j];
    }
    __syncthreads();
    if (tid == 0) g_nact[0] = n;
    if (tid >= 1 && tid <= MAXIT) g_nact[tid] = s_base[tid];
    __syncthreads();
    for (int e = tid; e < n; e += 256) {
        g_start[e] = s_start[e];
        int L = s_len[e];
        g_len[e] = L;
        int pos = atomicAdd(&s_base[L], 1);
        g_perm[pos] = e;
    }
}

// ---------------------------------------------------------------------------
__global__ __launch_bounds__(256)
void cast_bf(const float* __restrict__ src, ushort* __restrict__ dst, int n)
{
    int base = (blockIdx.x * 256 + threadIdx.x) * 4;
    if (base < n) {
        float4 v = *(const float4*)(src + base);
        ushort4 o;
        o.x = f2bf(v.x); o.y = f2bf(v.y); o.z = f2bf(v.z); o.w = f2bf(v.w);
        *(ushort4*)(dst + base) = o;
    }
}

// ---------------------------------------------------------------------------
// Transpose + cast ALL weight matrices (both kinds, all layers) in one launch.
// ---------------------------------------------------------------------------
__global__ __launch_bounds__(256)
void transcast_all(const float* __restrict__ Wi, const float* __restrict__ Wh,
                   ushort* __restrict__ WT_all, ushort* __restrict__ WhT_all)
{
    int z = blockIdx.z;
    int l = z >> 1;
    const float* src = ((z & 1) ? Wh : Wi) + (size_t)l * DD * ND3;
    ushort* dst = ((z & 1) ? WhT_all : WT_all) + (size_t)l * ND3 * DD;
    __shared__ float tile[64][65];
    int tid = threadIdx.x;
    int n0 = blockIdx.x * 64, k0 = blockIdx.y * 64;
#pragma unroll
    for (int i = 0; i < 16; ++i) {
        int idx = i * 256 + tid;
        int r = idx >> 6, c = idx & 63;
        tile[r][c] = src[(size_t)(k0 + r) * ND3 + n0 + c];
    }
    __syncthreads();
#pragma unroll
    for (int i = 0; i < 8; ++i) {
        int idx = i * 256 + tid;
        int nr = idx >> 5, kp = idx & 31;
        float a = tile[kp * 2][nr], b = tile[kp * 2 + 1][nr];
        unsigned pa = (unsigned)f2bf(a) | ((unsigned)f2bf(b) << 16);
        *(unsigned*)&dst[(size_t)(n0 + nr) * DD + k0 + kp * 2] = pa;
    }
}

// ---------------------------------------------------------------------------
// Phase A GEMM (bf16 MFMA): C[2048][3072] = A[2048][1024] * BT[3072][1024]^T
// 128x128 tile, 4 waves (2x2), BK=32, global_load_lds staging, XOR k-slot
// swizzle. Output stored as bf16. (verified in rounds 2-4)
// ---------------------------------------------------------------------------
__global__ __launch_bounds__(256)
void gemm_mfma(const ushort* __restrict__ A, const ushort* __restrict__ BT,
               ushort* __restrict__ C)
{
    __shared__ __align__(16) ushort As[128 * 32];
    __shared__ __align__(16) ushort Bs[128 * 32];
    int tid = threadIdx.x, lane = tid & 63, wv = tid >> 6;
    int m0 = blockIdx.y * 128, n0 = blockIdx.x * 128;
    int wr = wv >> 1, wc = wv & 1;
    f32x4 acc[4][4] = {};

    int ci0 = tid, ci1 = 256 + tid;
    int r0s = ci0 >> 2, r1s = ci1 >> 2;
    int ss0 = (ci0 & 3) ^ ((r0s >> 1) & 3);
    int ss1 = (ci1 & 3) ^ ((r1s >> 1) & 3);
    const ushort* Ar0 = A + (size_t)(m0 + r0s) * DD + ss0 * 8;
    const ushort* Ar1 = A + (size_t)(m0 + r1s) * DD + ss1 * 8;
    const ushort* Br0 = BT + (size_t)(n0 + r0s) * DD + ss0 * 8;
    const ushort* Br1 = BT + (size_t)(n0 + r1s) * DD + ss1 * 8;

    int g = lane >> 4, fr = lane & 15;

    for (int k0 = 0; k0 < DD; k0 += 32) {
        gld_lds16(Ar0 + k0, (char*)As + wv * 1024);
        gld_lds16(Ar1 + k0, (char*)As + 4096 + wv * 1024);
        gld_lds16(Br0 + k0, (char*)Bs + wv * 1024);
        gld_lds16(Br1 + k0, (char*)Bs + 4096 + wv * 1024);
        __syncthreads();

        bf16x8 af[4], bb[4];
#pragma unroll
        for (int mi = 0; mi < 4; ++mi) {
            int row = wr * 64 + mi * 16 + fr;
            int slot = g ^ ((row >> 1) & 3);
            af[mi] = *(const bf16x8*)(As + row * 32 + slot * 8);
        }
#pragma unroll
        for (int ni = 0; ni < 4; ++ni) {
            int row = wc * 64 + ni * 16 + fr;
            int slot = g ^ ((row >> 1) & 3);
            bb[ni] = *(const bf16x8*)(Bs + row * 32 + slot * 8);
        }
#pragma unroll
        for (int mi = 0; mi < 4; ++mi)
#pragma unroll
            for (int ni = 0; ni < 4; ++ni)
                acc[mi][ni] = __builtin_amdgcn_mfma_f32_16x16x32_bf16(
                    af[mi], bb[ni], acc[mi][ni], 0, 0, 0);
        __syncthreads();
    }

    int orow = (lane >> 4) * 4, ocol = lane & 15;
#pragma unroll
    for (int mi = 0; mi < 4; ++mi)
#pragma unroll
        for (int ni = 0; ni < 4; ++ni)
#pragma unroll
            for (int r2 = 0; r2 < 4; ++r2)
                C[(size_t)(m0 + wr * 64 + mi * 16 + orow + r2) * ND3 +
                  n0 + wc * 64 + ni * 16 + ocol] = f2bf(acc[mi][ni][r2]);
}

// ---------------------------------------------------------------------------
// Iteration 0: h_in = 0 (or last_states for the t==0 episode).
// ---------------------------------------------------------------------------
__global__ __launch_bounds__(256)
void it0_kernel(const ushort* __restrict__ xp, const float* __restrict__ Wh,
                const float* __restrict__ bh, const float* __restrict__ h0g,
                const int* __restrict__ term, float* __restrict__ Hnext,
                ushort* __restrict__ Hbfn, ushort* __restrict__ ybf,
                float* __restrict__ yf32, float* __restrict__ finals,
                const int* __restrict__ g_start, const int* __restrict__ g_perm,
                const int* __restrict__ g_nact)
{
    int M = g_nact[0];
    int r = blockIdx.x;
    if (r >= M) return;
    int e = g_perm[r];
    int t = g_start[e];
    int tid = threadIdx.x;
    bool useh0 = (t == 0) && (term[0] == 0);
    __shared__ float h0s[DD];
    __shared__ int s_nz;
    if (tid == 0) s_nz = 0;
    __syncthreads();
    if (useh0) {
        int nz = 0;
#pragma unroll
        for (int j = 0; j < 4; ++j) {
            float v = h0g[tid + j * 256];
            h0s[tid + j * 256] = v;
            nz |= (v != 0.f) ? 1 : 0;
        }
        if (nz) atomicOr(&s_nz, 1);
    }
    __syncthreads();
    bool gemv = useh0 && (s_nz != 0);
#pragma unroll
    for (int j = 0; j < 4; ++j) {
        int c = tid + j * 256;
        float hr = bh[c], hz = bh[DD + c], hn = bh[2 * DD + c];
        if (gemv) {
            for (int k = 0; k < DD; ++k) {
                float hv = h0s[k];
                hr += hv * Wh[(size_t)k * ND3 + c];
                hz += hv * Wh[(size_t)k * ND3 + DD + c];
                hn += hv * Wh[(size_t)k * ND3 + 2 * DD + c];
            }
        }
        float hp = useh0 ? h0s[c] : 0.f;
        float xr = bf2f(xp[(size_t)t * ND3 + c]);
        float xz = bf2f(xp[(size_t)t * ND3 + DD + c]);
        float xn = bf2f(xp[(size_t)t * ND3 + 2 * DD + c]);
        float hnew = gru_out(xr, xz, xn, hr, hz, hn, hp);
        Hnext[(size_t)e * DD + c] = hnew;
        Hbfn[(size_t)e * DD + c] = f2bf(hnew);
        if (yf32) yf32[(size_t)t * DD + c] = hnew;
        else      ybf[(size_t)t * DD + c] = f2bf(hnew);
        if (t == TT - 1) finals[c] = hnew;
    }
}

// ---------------------------------------------------------------------------
// Iteration i>=1 (MFMA, LDS-staged, BK=64):
// hp_gemm = Hbf_active @ WhT^T, fused gates + state update.
// 512 threads / 8 waves. Tile: 32 rows x (64 hcols x 3 gates). BK=64.
// LDS: As[32][64] (4KB), Bs[192][64] (24KB). global_load_lds 16B staging with
// XOR slot swizzle (slot ^= row&7) applied on the GLOBAL source (LDS linear)
// and mirrored on the ds_read side. 16 k-steps, 2 barriers each.
// ---------------------------------------------------------------------------
__global__ __launch_bounds__(512)
void iter_mfma(int it, const float* __restrict__ Hp, float* __restrict__ Hn,
               const ushort* __restrict__ Hbfp, ushort* __restrict__ Hbfn,
               const ushort* __restrict__ xp, const ushort* __restrict__ WhT,
               const float* __restrict__ bh, ushort* __restrict__ ybf,
               float* __restrict__ yf32, float* __restrict__ finals,
               const int* __restrict__ g_start, const int* __restrict__ g_perm,
               const int* __restrict__ g_nact)
{
    int M = g_nact[it];
    int r0 = blockIdx.y * 32;
    if (r0 >= M) return;
    int c0 = blockIdx.x * 64;
    __shared__ __align__(16) ushort As[32 * 64];    // 4 KB
    __shared__ __align__(16) ushort Bs[192 * 64];   // 24 KB
    __shared__ int s_e[32], s_t[32], s_v[32];
    int tid = threadIdx.x, lane = tid & 63, wv = tid >> 6;

    if (tid < 32) {
        int r = r0 + tid;
        int v = (r < M) ? 1 : 0;
        int e = v ? g_perm[r] : 0;
        s_e[tid] = e;
        s_v[tid] = v;
        s_t[tid] = v ? (g_start[e] + it) : 0;
    }

    // A staging (chunks 0..255, waves 0-3): chunk=tid -> row=tid>>3, slot=tid&7
    const ushort* srcA = Hbfp;
    if (tid < 256) {
        int row = tid >> 3;
        int rr = r0 + row; if (rr > M - 1) rr = M - 1;
        int eA = g_perm[rr];
        int sl = (tid & 7) ^ (row & 7);
        srcA = Hbfp + (size_t)eA * DD + sl * 8;
    }
    // B staging: 3 passes of 512 chunks; pass p chunk = p*512+tid
    const ushort* srcB[3];
#pragma unroll
    for (int p = 0; p < 3; ++p) {
        int c = p * 512 + tid;
        int j = c >> 3;                 // 0..191
        int f = j >> 6;
        int coln = c0 + (j & 63);
        int sl = (c & 7) ^ (j & 7);
        srcB[p] = WhT + (size_t)(f * DD + coln) * DD + sl * 8;
    }

    int fr = lane & 15, g = lane >> 4;
    int rw = (wv & 1) * 16, hw = (wv >> 1) * 16;
    f32x4 acc[3] = {};

    for (int k0 = 0; k0 < DD; k0 += 64) {
        if (tid < 256) gld_lds16(srcA + k0, (char*)As + wv * 1024);
        gld_lds16(srcB[0] + k0, (char*)Bs + wv * 1024);
        gld_lds16(srcB[1] + k0, (char*)Bs + 8192 + wv * 1024);
        gld_lds16(srcB[2] + k0, (char*)Bs + 16384 + wv * 1024);
        __syncthreads();

        int arow = rw + fr;
#pragma unroll
        for (int kw = 0; kw < 2; ++kw) {
            int sA = (kw * 4 + g) ^ (arow & 7);
            bf16x8 af = *(const bf16x8*)(As + arow * 64 + sA * 8);
#pragma unroll
            for (int f = 0; f < 3; ++f) {
                int jf = f * 64 + hw + fr;
                int sB = (kw * 4 + g) ^ (jf & 7);
                bf16x8 bb = *(const bf16x8*)(Bs + jf * 64 + sB * 8);
                acc[f] = __builtin_amdgcn_mfma_f32_16x16x32_bf16(af, bb, acc[f], 0, 0, 0);
            }
        }
        __syncthreads();
    }

    int col = c0 + hw + fr;
#pragma unroll
    for (int r2 = 0; r2 < 4; ++r2) {
        int row = rw + g * 4 + r2;
        if (!s_v[row]) continue;
        int e = s_e[row], t = s_t[row];
        float hr = acc[0][r2] + bh[col];
        float hz = acc[1][r2] + bh[DD + col];
        float hn = acc[2][r2] + bh[2 * DD + col];
        float xr = bf2f(xp[(size_t)t * ND3 + col]);
        float xz = bf2f(xp[(size_t)t * ND3 + DD + col]);
        float xn = bf2f(xp[(size_t)t * ND3 + 2 * DD + col]);
        float hp = Hp[(size_t)e * DD + col];
        float hnew = gru_out(xr, xz, xn, hr, hz, hn, hp);
        Hn[(size_t)e * DD + col] = hnew;
        Hbfn[(size_t)e * DD + col] = f2bf(hnew);
        if (yf32) yf32[(size_t)t * DD + col] = hnew;
        else      ybf[(size_t)t * DD + col] = f2bf(hnew);
        if (t == TT - 1) finals[col] = hnew;
    }
}

// ---------------------------------------------------------------------------
// Cleanup: serially finish any episode with len > MAXIT (normally none/few).
// ---------------------------------------------------------------------------
__global__ __launch_bounds__(256)
void cleanup_kernel(const float* __restrict__ Hlast, const ushort* __restrict__ xp,
                    const float* __restrict__ Wh, const float* __restrict__ bh,
                    ushort* __restrict__ ybf, float* __restrict__ yf32,
                    float* __restrict__ finals, const int* __restrict__ g_start,
                    const int* __restrict__ g_len, const int* __restrict__ g_perm,
                    const int* __restrict__ g_nact)
{
    int Mt = g_nact[MAXIT];
    if (Mt == 0) return;
    __shared__ float h[DD];
    int tid = threadIdx.x;
    for (int r = blockIdx.x; r < Mt; r += gridDim.x) {
        int e = g_perm[r];
        int s0 = g_start[e];
        int L = g_len[e];
#pragma unroll
        for (int j = 0; j < 4; ++j) h[tid + j * 256] = Hlast[(size_t)e * DD + tid + j * 256];
        __syncthreads();
        for (int i = MAXIT; i < L; ++i) {
            int t = s0 + i;
            float hnew[4];
#pragma unroll
            for (int j = 0; j < 4; ++j) {
                int c = tid + j * 256;
                float hr = bh[c], hz = bh[DD + c], hn = bh[2 * DD + c];
                for (int k = 0; k < DD; ++k) {
                    float hv = h[k];
                    hr += hv * Wh[(size_t)k * ND3 + c];
                    hz += hv * Wh[(size_t)k * ND3 + DD + c];
                    hn += hv * Wh[(size_t)k * ND3 + 2 * DD + c];
                }
                float xr = bf2f(xp[(size_t)t * ND3 + c]);
                float xz = bf2f(xp[(size_t)t * ND3 + DD + c]);
                float xn = bf2f(xp[(size_t)t * ND3 + 2 * DD + c]);
                float hp = h[c];
                hnew[j] = gru_out(xr, xz, xn, hr, hz, hn, hp);
                if (yf32) yf32[(size_t)t * DD + c] = hnew[j];
                else      ybf[(size_t)t * DD + c] = f2bf(hnew[j]);
                if (t == TT - 1) finals[c] = hnew[j];
            }
            __syncthreads();
#pragma unroll
            for (int j = 0; j < 4; ++j) h[tid + j * 256] = hnew[j];
            __syncthreads();
        }
        __syncthreads();
    }
}

// ---------------------------------------------------------------------------
extern "C" void kernel_launch(void* const* d_in, const int* in_sizes, int n_in,
                              void* d_out, int out_size, void* d_ws, size_t ws_size,
                              hipStream_t stream)
{
    const float* x_in = (const float*)d_in[0];
    const int*   term = (const int*)d_in[1];
    const float* h0   = (const float*)d_in[2];
    const float* Wi   = (const float*)d_in[3];
    const float* Wh   = (const float*)d_in[4];
    const float* bh   = (const float*)d_in[5];
    float* out = (float*)d_out;

    ushort* xp      = (ushort*)d_ws;                      // TT*ND3 bf16
    float*  Hb0     = (float*)(xp + (size_t)TT * ND3);    // TT*DD fp32
    float*  Hb1     = Hb0 + (size_t)TT * DD;              // TT*DD fp32
    ushort* Hbf0    = (ushort*)(Hb1 + (size_t)TT * DD);   // TT*DD bf16
    ushort* Hbf1    = Hbf0 + (size_t)TT * DD;             // TT*DD bf16
    ushort* Xbf     = Hbf1 + (size_t)TT * DD;             // TT*DD bf16
    ushort* Yb0     = Xbf + (size_t)TT * DD;              // TT*DD bf16
    ushort* Yb1     = Yb0 + (size_t)TT * DD;              // TT*DD bf16
    ushort* WT_all  = Yb1 + (size_t)TT * DD;              // LL*ND3*DD bf16
    ushort* WhT_all = WT_all + (size_t)LL * ND3 * DD;     // LL*ND3*DD bf16
    int* ib      = (int*)(WhT_all + (size_t)LL * ND3 * DD);
    int* g_start = ib;
    int* g_len   = ib + TT;
    int* g_perm  = ib + 2 * TT;
    int* g_nact  = ib + 3 * TT;

    seg_kernel<<<1, 256, 0, stream>>>(term, g_start, g_len, g_perm, g_nact);
    cast_bf<<<(TT * DD / 4 + 255) / 256, 256, 0, stream>>>(x_in, Xbf, TT * DD);
    transcast_all<<<dim3(ND3 / 64, DD / 64, 2 * LL), 256, 0, stream>>>(
        Wi, Wh, WT_all, WhT_all);

    const ushort* Abf[4] = { Xbf, Yb0, Yb1, Yb0 };
    ushort*       Ybo[4] = { Yb0, Yb1, Yb0, nullptr };

    for (int l = 0; l < LL; ++l) {
        const float* Whl = Wh + (size_t)l * DD * ND3;
        const float* bhl = bh + (size_t)l * ND3;
        const ushort* WTl  = WT_all + (size_t)l * ND3 * DD;
        const ushort* WhTl = WhT_all + (size_t)l * ND3 * DD;
        float* yf32 = (l == LL - 1) ? out : nullptr;
        ushort* ybf = Ybo[l];
        float* finals = out + (size_t)TT * DD + (size_t)l * DD;

        gemm_mfma<<<dim3(ND3 / 128, TT / 128), 256, 0, stream>>>(Abf[l], WTl, xp);

        it0_kernel<<<TT, 256, 0, stream>>>(xp, Whl, bhl, h0 + (size_t)l * DD, term,
                                           Hb0, Hbf0, ybf, yf32, finals,
                                           g_start, g_perm, g_nact);

        for (int it = 1; it < MAXIT; ++it) {
            float*  Hp   = (it & 1) ? Hb0 : Hb1;
            float*  Hn   = (it & 1) ? Hb1 : Hb0;
            ushort* Hbfp = (it & 1) ? Hbf0 : Hbf1;
            ushort* Hbfn = (it & 1) ? Hbf1 : Hbf0;
            int maxrows = TT / (it + 1);
            dim3 grd(DD / 64, (maxrows + 31) / 32);
            iter_mfma<<<grd, 512, 0, stream>>>(it, Hp, Hn, Hbfp, Hbfn, xp, WhTl,
                                               bhl, ybf, yf32, finals,
                                               g_start, g_perm, g_nact);
        }

        float* Hlast = ((MAXIT - 1) & 1) ? Hb1 : Hb0;
        cleanup_kernel<<<64, 256, 0, stream>>>(Hlast, xp, Whl, bhl, ybf, yf32,
                                               finals, g_start, g_len, g_perm,
                                               g_nact);
    }
}